// Round 4
// baseline (175.914 us; speedup 1.0000x reference)
//
#include <hip/hip_runtime.h>
#include <hip/hip_bf16.h>
#include <stdint.h>

#define NN 4096
#define DD 512
#define NCLS 512
#define LMARGIN 0.3f
#define NSLOT 128

typedef float f32x4 __attribute__((ext_vector_type(4)));
typedef __bf16 bf16x8 __attribute__((ext_vector_type(8)));
typedef unsigned short us8 __attribute__((ext_vector_type(8)));
typedef unsigned int u32;

__device__ __forceinline__ float waveSum(float v) {
#pragma unroll
    for (int s = 32; s > 0; s >>= 1) v += __shfl_down(v, s, 64);
    return v;
}

// ---------- init: partial-max/min identity values ----------
__global__ void k_init(float* __restrict__ pMax, float* __restrict__ pMin) {
    int i = blockIdx.x * 256 + threadIdx.x;   // grid covers NN*NSLOT = 524288
    pMax[i] = 0.f;
    pMin[i] = __builtin_inff();
}

// ---------- per-row: bf16 cast (vectorized) + squared norm ----------
__global__ void k_prep(const float* __restrict__ x, __hip_bfloat16* __restrict__ xb,
                       float* __restrict__ sq) {
    int tid = threadIdx.x;
    int lane = tid & 63, wave = tid >> 6;
    int r = blockIdx.x * 4 + wave;            // grid 1024 x 256: one row per wave
    const f32x4* px = (const f32x4*)(x + (size_t)r * DD) + lane * 2;
    f32x4 v0 = px[0], v1 = px[1];
    float s = v0.x * v0.x + v0.y * v0.y + v0.z * v0.z + v0.w * v0.w +
              v1.x * v1.x + v1.y * v1.y + v1.z * v1.z + v1.w * v1.w;
    us8 o;
    o[0] = __builtin_bit_cast(unsigned short, __float2bfloat16(v0.x));
    o[1] = __builtin_bit_cast(unsigned short, __float2bfloat16(v0.y));
    o[2] = __builtin_bit_cast(unsigned short, __float2bfloat16(v0.z));
    o[3] = __builtin_bit_cast(unsigned short, __float2bfloat16(v0.w));
    o[4] = __builtin_bit_cast(unsigned short, __float2bfloat16(v1.x));
    o[5] = __builtin_bit_cast(unsigned short, __float2bfloat16(v1.y));
    o[6] = __builtin_bit_cast(unsigned short, __float2bfloat16(v1.z));
    o[7] = __builtin_bit_cast(unsigned short, __float2bfloat16(v1.w));
    *(us8*)((unsigned short*)xb + (size_t)r * DD + lane * 8) = o;
    s = waveSum(s);
    if (lane == 0) sq[r] = s;
}

// ---------- per-class sums, no atomics: one block per class ----------
__global__ void k_csum(const float* __restrict__ x, const int* __restrict__ tgt,
                       float* __restrict__ classSum, float* __restrict__ classCnt) {
    int c = blockIdx.x, tid = threadIdx.x;    // 512 blocks x 256 threads
    __shared__ int list[128];
    __shared__ int lcnt;
    if (tid == 0) lcnt = 0;
    __syncthreads();
    for (int i = tid; i < NN; i += 256) {
        if (tgt[i] == c) {
            int p = atomicAdd(&lcnt, 1);      // LDS atomic — cheap
            list[p] = i;
        }
    }
    __syncthreads();
    int n = lcnt;
    float s0 = 0.f, s1 = 0.f;
    for (int p = 0; p < n; ++p) {
        const float* row = x + (size_t)list[p] * DD;
        s0 += row[tid];
        s1 += row[tid + 256];
    }
    classSum[(size_t)c * DD + tid] = s0;
    classSum[(size_t)c * DD + tid + 256] = s1;
    if (tid == 0) classCnt[c] = (float)n;
}

// ---------- totalSum[d] = sum_c classSum[c][d] ----------
__global__ void k_totsum(const float* __restrict__ classSum, float* __restrict__ totalSum) {
    int d = blockIdx.x * 256 + threadIdx.x;   // grid 2 x 256 = 512 = DD
    float s = 0.f;
#pragma unroll 8
    for (int c = 0; c < NCLS; ++c) s += classSum[(size_t)c * DD + d];
    totalSum[d] = s;
}

// ---------- Gram (bf16 MFMA, global-direct fragments, no LDS, no barriers) ----------
__global__ __launch_bounds__(256) void k_gram(const __hip_bfloat16* __restrict__ xb,
                                              const float* __restrict__ sq,
                                              const int* __restrict__ tgt,
                                              float* __restrict__ pMax,
                                              float* __restrict__ pMin) {
    // linear triangular grid: 528 blocks -> (by, bx) with by <= bx
    int b = blockIdx.x;
    int by = 0, rem = b;
    while (rem >= 32 - by) { rem -= 32 - by; ++by; }
    int bx = by + rem;

    const int tid = threadIdx.x;
    const int lane = tid & 63, wave = tid >> 6;
    const int wr = wave >> 1, wc = wave & 1;
    const int l15 = lane & 15, quad = lane >> 4;

    // A-fragment (16x16x32 bf16): row = l15, k = quad*8 + j  -> contiguous 16B of X
    const __hip_bfloat16* pA = xb + (size_t)(by * 128 + wr * 64 + l15) * DD + quad * 8;
    const __hip_bfloat16* pB = xb + (size_t)(bx * 128 + wc * 64 + l15) * DD + quad * 8;

    f32x4 acc[4][4];
    const f32x4 fz = {0.f, 0.f, 0.f, 0.f};
#pragma unroll
    for (int i = 0; i < 4; ++i)
#pragma unroll
        for (int j = 0; j < 4; ++j) acc[i][j] = fz;

    bf16x8 a0[4], b0[4], a1[4], b1[4];
#pragma unroll
    for (int i = 0; i < 4; ++i) a0[i] = *(const bf16x8*)(pA + (size_t)i * 16 * DD);
#pragma unroll
    for (int j = 0; j < 4; ++j) b0[j] = *(const bf16x8*)(pB + (size_t)j * 16 * DD);

    for (int k0 = 0; k0 < DD; k0 += 32) {
        int kn = (k0 + 32 < DD) ? k0 + 32 : k0;   // last iter: dummy re-load
#pragma unroll
        for (int i = 0; i < 4; ++i) a1[i] = *(const bf16x8*)(pA + (size_t)i * 16 * DD + kn);
#pragma unroll
        for (int j = 0; j < 4; ++j) b1[j] = *(const bf16x8*)(pB + (size_t)j * 16 * DD + kn);
#pragma unroll
        for (int i = 0; i < 4; ++i)
#pragma unroll
            for (int j = 0; j < 4; ++j)
                acc[i][j] = __builtin_amdgcn_mfma_f32_16x16x32_bf16(a0[i], b0[j], acc[i][j], 0, 0, 0);
#pragma unroll
        for (int i = 0; i < 4; ++i) { a0[i] = a1[i]; b0[i] = b1[i]; }
    }

    // epilogue: dist = sqrt(max(sq[r]+sq[c]-2G, 1e-12)); masked max/min -> partial slots.
    // Slot layout (all writers unique): row-stats -> bx*2+wc (0..63);
    // col-stats -> 64 + by*2+wr (64..127).
    const int r0 = by * 128 + wr * 64;
    const int c0 = bx * 128 + wc * 64;
    const int rowSlot = bx * 2 + wc;
    const int colSlot = 64 + by * 2 + wr;
    float sqc[4];
    int tct[4];
#pragma unroll
    for (int j = 0; j < 4; ++j) {
        int c = c0 + j * 16 + l15;
        sqc[j] = sq[c];
        tct[j] = tgt[c];
    }
    float cmaxv[4], cminv[4];
#pragma unroll
    for (int j = 0; j < 4; ++j) { cmaxv[j] = 0.f; cminv[j] = __builtin_inff(); }

#pragma unroll
    for (int i = 0; i < 4; ++i) {
#pragma unroll
        for (int rg = 0; rg < 4; ++rg) {
            int r = r0 + i * 16 + quad * 4 + rg;
            float sqr = sq[r];
            int rt = tgt[r];
            float rmaxv = 0.f, rminv = __builtin_inff();
#pragma unroll
            for (int j = 0; j < 4; ++j) {
                float g = acc[i][j][rg];
                float dist = sqrtf(fmaxf(sqr + sqc[j] - 2.0f * g, 1e-12f));
                if (rt == tct[j]) {
                    rmaxv = fmaxf(rmaxv, dist);
                    cmaxv[j] = fmaxf(cmaxv[j], dist);
                } else {
                    rminv = fminf(rminv, dist);
                    cminv[j] = fminf(cminv[j], dist);
                }
            }
#pragma unroll
            for (int s = 1; s < 16; s <<= 1) {
                rmaxv = fmaxf(rmaxv, __shfl_xor(rmaxv, s, 64));
                rminv = fminf(rminv, __shfl_xor(rminv, s, 64));
            }
            if (l15 == 0) {   // plain stores — unique slot per (block, wave)
                pMax[(size_t)r * NSLOT + rowSlot] = rmaxv;
                pMin[(size_t)r * NSLOT + rowSlot] = rminv;
            }
        }
    }
    // column stats (transposed element): reduce across quads
#pragma unroll
    for (int j = 0; j < 4; ++j) {
        float vmax = cmaxv[j], vmin = cminv[j];
        vmax = fmaxf(vmax, __shfl_xor(vmax, 16, 64));
        vmax = fmaxf(vmax, __shfl_xor(vmax, 32, 64));
        vmin = fminf(vmin, __shfl_xor(vmin, 16, 64));
        vmin = fminf(vmin, __shfl_xor(vmin, 32, 64));
        if (quad == 0) {
            int c = c0 + j * 16 + l15;
            pMax[(size_t)c * NSLOT + colSlot] = vmax;
            pMin[(size_t)c * NSLOT + colSlot] = vmin;
        }
    }
}

// ---------- per-row centroid losses + triplet terms + partial-slot reduce ----------
__global__ void k_rowloss(const float* __restrict__ x, const int* __restrict__ tgt,
                          const float* __restrict__ classSum, const float* __restrict__ classCnt,
                          const float* __restrict__ totalSum, const float* __restrict__ pMax,
                          const float* __restrict__ pMin,
                          float* __restrict__ tlArr, float* __restrict__ ctlArr,
                          float* __restrict__ dccArr) {
    int i = blockIdx.x, tid = threadIdx.x;  // 256 threads
    int lane = tid & 63;
    int t = tgt[i];
    float cnt = classCnt[t];
    float rcp = 1.0f / cnt;
    float rcn = 1.0f / ((float)NN - cnt);
    float scp = 0.f, scn = 0.f, scc = 0.f;
#pragma unroll
    for (int jj = 0; jj < 2; ++jj) {
        int d = tid + jj * 256;
        float xv = x[(size_t)i * DD + d];
        float cs = classSum[t * DD + d];
        float ts = totalSum[d];
        float ic = cs * rcp;
        float oc = (ts - cs) * rcn;
        float a = ic - xv, b2 = oc - xv, c = ic - oc;
        scp += a * a;
        scn += b2 * b2;
        scc += c * c;
    }
    scp = waveSum(scp);
    scn = waveSum(scn);
    scc = waveSum(scc);
    __shared__ float red[4][3];
    __shared__ float mred[4];   // [0,1]=max halves, [2,3]=min halves
    int w = tid >> 6;
    if ((tid & 63) == 0) { red[w][0] = scp; red[w][1] = scn; red[w][2] = scc; }
    // triplet partial-slot reduction over NSLOT=128 slots:
    // waves 0,1 -> max over pMax[0..127]; waves 2,3 -> min over pMin[0..127]
    if (w < 2) {
        float m = pMax[(size_t)i * NSLOT + w * 64 + lane];
#pragma unroll
        for (int s = 32; s > 0; s >>= 1) m = fmaxf(m, __shfl_down(m, s, 64));
        if (lane == 0) mred[w] = m;
    } else {
        float m = pMin[(size_t)i * NSLOT + (w - 2) * 64 + lane];
#pragma unroll
        for (int s = 32; s > 0; s >>= 1) m = fminf(m, __shfl_down(m, s, 64));
        if (lane == 0) mred[w] = m;
    }
    __syncthreads();
    if (tid == 0) {
        float p = red[0][0] + red[1][0] + red[2][0] + red[3][0];
        float n2 = red[0][1] + red[1][1] + red[2][1] + red[3][1];
        float cc = red[0][2] + red[1][2] + red[2][2] + red[3][2];
        float dcp = sqrtf(p), dcn = sqrtf(n2), dcc = sqrtf(cc);
        float ap = fmaxf(mred[0], mred[1]);
        float an = fminf(mred[2], mred[3]);
        tlArr[i] = fmaxf(ap - an + LMARGIN, 0.f);
        ctlArr[i] = fmaxf(dcp - dcn + LMARGIN, 0.f);
        dccArr[i] = dcc;
    }
}

// ---------- single-block final reduction over 3 x NN values ----------
__global__ __launch_bounds__(1024) void k_reduce(const float* __restrict__ tlArr,
                                                 const float* __restrict__ ctlArr,
                                                 const float* __restrict__ dccArr,
                                                 float* __restrict__ out) {
    int tid = threadIdx.x;  // 1024 threads
    float s0 = 0.f, s1 = 0.f, s2 = 0.f;
#pragma unroll
    for (int jj = 0; jj < NN / 1024; ++jj) {
        int i = tid + jj * 1024;
        s0 += tlArr[i];
        s1 += ctlArr[i];
        s2 += dccArr[i];
    }
    s0 = waveSum(s0);
    s1 = waveSum(s1);
    s2 = waveSum(s2);
    __shared__ float red[16][3];
    int w = tid >> 6;
    if ((tid & 63) == 0) { red[w][0] = s0; red[w][1] = s1; red[w][2] = s2; }
    __syncthreads();
    if (tid == 0) {
        float a = 0.f, b = 0.f, c = 0.f;
#pragma unroll
        for (int k = 0; k < 16; ++k) { a += red[k][0]; b += red[k][1]; c += red[k][2]; }
        out[0] = a * (1.0f / NN);
        out[1] = b * (1.0f / NN);
        out[2] = -c * (1.0f / NN);
    }
}

extern "C" void kernel_launch(void* const* d_in, const int* in_sizes, int n_in,
                              void* d_out, int out_size, void* d_ws, size_t ws_size,
                              hipStream_t stream) {
    const float* x = (const float*)d_in[0];
    const int* tgt = (const int*)d_in[1];
    float* out = (float*)d_out;
    char* ws = (char*)d_ws;

    size_t o = 0;
    __hip_bfloat16* xb = (__hip_bfloat16*)(ws + o); o += (size_t)NN * DD * 2;  // 4 MB
    float* sq = (float*)(ws + o);       o += (size_t)NN * 4;
    float* classSum = (float*)(ws + o); o += (size_t)NCLS * DD * 4;            // 1 MB
    float* classCnt = (float*)(ws + o); o += (size_t)NCLS * 4;
    float* totalSum = (float*)(ws + o); o += (size_t)DD * 4;
    float* pMax = (float*)(ws + o);     o += (size_t)NN * NSLOT * 4;           // 2 MB
    float* pMin = (float*)(ws + o);     o += (size_t)NN * NSLOT * 4;           // 2 MB
    float* tlArr = (float*)(ws + o);    o += (size_t)NN * 4;
    float* ctlArr = (float*)(ws + o);   o += (size_t)NN * 4;
    float* dccArr = (float*)(ws + o);   o += (size_t)NN * 4;

    k_init<<<dim3((NN * NSLOT) / 256), dim3(256), 0, stream>>>(pMax, pMin);
    k_prep<<<dim3(NN / 4), dim3(256), 0, stream>>>(x, xb, sq);
    k_csum<<<dim3(NCLS), dim3(256), 0, stream>>>(x, tgt, classSum, classCnt);
    k_totsum<<<dim3(2), dim3(256), 0, stream>>>(classSum, totalSum);
    k_gram<<<dim3(528), dim3(256), 0, stream>>>(xb, sq, tgt, pMax, pMin);
    k_rowloss<<<dim3(NN), dim3(256), 0, stream>>>(x, tgt, classSum, classCnt, totalSum,
                                                  pMax, pMin, tlArr, ctlArr, dccArr);
    k_reduce<<<dim3(1), dim3(1024), 0, stream>>>(tlArr, ctlArr, dccArr, out);
}